// Round 11
// baseline (178.470 us; speedup 1.0000x reference)
//
#include <hip/hip_runtime.h>
#include <hip/hip_fp16.h>

typedef _Float16 f16x8 __attribute__((ext_vector_type(8)));
typedef float f32x4 __attribute__((ext_vector_type(4)));

// ---------------- workspace layout (bytes) ----------------
#define WS_X0U   0            // 256*64*4   = 65536      x0u f32 [c][64]
#define WS_GHP   65536        // 8192*256*2 = 4194304    Ghp f16 frag-packed [n][c]
#define WS_W2P   4259840      // 73728*2    = 147456     w2 f16 frag-packed
#define WS_WH    4407296      // 2048*512*2 = 2097152    w f16 [b][k]
#define WS_AFTH  6504448      // 384*512*2  = 393216     affine wt f16 [f][k]
#define WS_W2TH  6897664      // 192*384*2  = 147456     sum_k W^2 f16 [o][k]
#define WS_S1P   7045120      // 2048*256*2 = 1048576    style1 f16 frag-packed
#define WS_S2H   8093696      // 2048*128*2 = 524288     style2 f16 [b][c]
#define WS_SSQ   8617984      // 2048*384*2 = 1572864    style^2 f16 [b][f]
#define WS_D1    10190848     // 2048*128*4 = 1048576    demod1
#define WS_D2    11239424     // 2048*64*4  = 524288     demod2
#define WS_X1T   11763712     // 2048*64*128*2 = 33554432  x1t f16 [b][p][o] PRE-MODULATED
// end 45318144

// bilinear x2, half-pixel centers
__device__ __forceinline__ void up_wi(int j, int S, int& i0, int& i1,
                                      float& w0, float& w1) {
  int m = j >> 1;
  if (j & 1) { i0 = m; i1 = (m + 1 < S) ? m + 1 : S - 1; w0 = 0.75f; w1 = 0.25f; }
  else       { i0 = (m - 1 >= 0) ? m - 1 : 0; i1 = m;     w0 = 0.25f; w1 = 0.75f; }
}

// xq LDS addressing: pixel-pair layout, 8 slots/pair, XOR swizzle.
// units: ushorts. pair = 64 ushorts (8 slots x 8), slot = ((pix&1)*4+i)^((pix>>1)&7)
__device__ __forceinline__ int xq_off(int pix, int i) {
  return (pix >> 1) * 64 + (((((pix & 1) << 2) + i) ^ ((pix >> 1) & 7)) << 3);
}

// ---------------- K0: init conv + lrelu + upsample 4->8 ----------------
// grid 256 (o), block 256 = 16 pix x 16 cgroups(32ch). 2-stage LDS reduce.
__global__ __launch_bounds__(256) void k_init(const float* __restrict__ ic,
    const float* __restrict__ w0c, const float* __restrict__ b0,
    float* __restrict__ x0u) {
  int o = blockIdx.x, t = threadIdx.x;
  int pix = t & 15, cg = t >> 4;
  int py = pix >> 2, px = pix & 3;
  __shared__ float part[16][17];
  __shared__ float x4[16];
  float acc = 0.f;
  int c0 = cg * 32;
  for (int c = c0; c < c0 + 32; ++c) {
    const float* wp = w0c + (o * 512 + c) * 9;
    const float* xp = ic + c * 16;
#pragma unroll
    for (int dy = 0; dy < 3; ++dy) {
      int iy = py + dy - 1;
      if ((unsigned)iy >= 4u) continue;
#pragma unroll
      for (int dx = 0; dx < 3; ++dx) {
        int ix = px + dx - 1;
        if ((unsigned)ix >= 4u) continue;
        acc += wp[dy * 3 + dx] * xp[iy * 4 + ix];
      }
    }
  }
  part[cg][pix] = acc;
  __syncthreads();
  if (t < 16) {
    float v = b0[o];
#pragma unroll
    for (int g = 0; g < 16; ++g) v += part[g][t];
    x4[t] = (v >= 0.f) ? v : 0.2f * v;
  }
  __syncthreads();
  if (t < 64) {
    int oy = t >> 3, ox = t & 7;
    int y0, y1, xx0, xx1; float wy0, wy1, wx0, wx1;
    up_wi(oy, 4, y0, y1, wy0, wy1);
    up_wi(ox, 4, xx0, xx1, wx0, wx1);
    float v = wy0 * (wx0 * x4[y0 * 4 + xx0] + wx1 * x4[y0 * 4 + xx1])
            + wy1 * (wx0 * x4[y1 * 4 + xx0] + wx1 * x4[y1 * 4 + xx1]);
    x0u[o * 64 + t] = v;
  }
}

// ---------------- K_prep: Ghp[n=p*128+o][c] frag-packed f16 --------------
// grid (128 o, 4 pgroup), block 256 (c)
__global__ __launch_bounds__(256) void k_prep(const float* __restrict__ w1c,
    const float* __restrict__ x0u, _Float16* __restrict__ Ghp) {
  int o = blockIdx.x, pg = blockIdx.y, t = threadIdx.x;
  __shared__ _Float16 x0l[256][66];
  for (int i = t; i < 256 * 64; i += 256) {
    int c = i >> 6, p = i & 63;
    x0l[c][p] = (_Float16)x0u[i];
  }
  __syncthreads();
  int c = t;
  float wr9[9];
#pragma unroll
  for (int k = 0; k < 9; ++k) wr9[k] = w1c[(o * 256 + c) * 9 + k];
  int cpart = ((((c >> 3) & 3) * 16 + (o & 15)) * 8) + (c & 7);
  int cq = c >> 5, oq = o >> 4;
  for (int p = pg * 16; p < pg * 16 + 16; ++p) {
    int py = p >> 3, px = p & 7;
    float acc = 0.f;
#pragma unroll
    for (int dy = 0; dy < 3; ++dy) {
      int iy = py + dy - 1;
      if ((unsigned)iy >= 8u) continue;
#pragma unroll
      for (int dx = 0; dx < 3; ++dx) {
        int ix = px + dx - 1;
        if ((unsigned)ix >= 8u) continue;
        acc += wr9[dy * 3 + dx] * (float)x0l[c][iy * 8 + ix];
      }
    }
    Ghp[((p * 8 + oq) * 8 + cq) * 512 + cpart] = (_Float16)acc;
  }
}

// ---------------- K_misc: w2p, wh, afTh, W2Th ----------------------------
// grid 5440, block 256
__global__ __launch_bounds__(256) void k_misc(const float* __restrict__ w1c,
    const float* __restrict__ w2c, const float* __restrict__ a1w,
    const float* __restrict__ a2w, const float* __restrict__ wsrc,
    _Float16* __restrict__ w2p, _Float16* __restrict__ wh,
    _Float16* __restrict__ afTh, _Float16* __restrict__ W2Th) {
  int idx = blockIdx.x * 256 + threadIdx.x;
  if (idx < 73728) {
    int tap = idx / 8192, r = idx & 8191;
    int kg = r >> 11, mf = (r >> 9) & 3, l = (r >> 3) & 63, j = r & 7;
    int o = mf * 16 + (l & 15);
    int c = kg * 32 + (l >> 4) * 8 + j;
    w2p[idx] = (_Float16)w2c[(o * 128 + c) * 9 + tap];
  } else if (idx < 73728 + 1048576) {
    int i = idx - 73728;
    wh[i] = (_Float16)wsrc[i];
  } else if (idx < 73728 + 1048576 + 196608) {
    int i = idx - 73728 - 1048576;         // i = f*512 + k
    afTh[i] = (_Float16)((i < 131072) ? a1w[i] : a2w[i - 131072]);
  } else if (idx < 73728 + 1048576 + 196608 + 73728) {
    int i = idx - 73728 - 1048576 - 196608;  // i = o*384 + k
    int o = i / 384, k = i - o * 384;
    float v = 0.f;
    const float* wp = nullptr;
    if (o < 128 && k < 256)        wp = w1c + (o * 256 + k) * 9;
    else if (o >= 128 && k >= 256) wp = w2c + ((o - 128) * 128 + (k - 256)) * 9;
    if (wp) {
#pragma unroll
      for (int q = 0; q < 9; ++q) v += wp[q] * wp[q];
    }
    W2Th[i] = (_Float16)v;
  }
}

// ---------------- K_sty: styles MFMA GEMM M=2048 N=384 K=512 -------------
// grid (6, 32), block 256 (4 waves 2x2), tile 64x64
__global__ __launch_bounds__(256) void k_sty(const _Float16* __restrict__ wh,
    const _Float16* __restrict__ afTh, const float* __restrict__ a1b,
    const float* __restrict__ a2b, _Float16* __restrict__ s1p,
    _Float16* __restrict__ s2h, _Float16* __restrict__ ssq) {
  int t = threadIdx.x, lane = t & 63, w = t >> 6;
  int wr = w >> 1, wc = w & 1;
  int b0 = blockIdx.y * 64 + wr * 32;
  int f0 = blockIdx.x * 64 + wc * 32;
  f32x4 acc[2][2] = {};
  int lr = lane & 15, lk = (lane >> 4) * 8;
#pragma unroll
  for (int kg = 0; kg < 16; ++kg) {
    f16x8 af[2], bf[2];
#pragma unroll
    for (int mf = 0; mf < 2; ++mf)
      af[mf] = *(const f16x8*)(wh + (b0 + mf * 16 + lr) * 512 + kg * 32 + lk);
#pragma unroll
    for (int nf = 0; nf < 2; ++nf)
      bf[nf] = *(const f16x8*)(afTh + (f0 + nf * 16 + lr) * 512 + kg * 32 + lk);
#pragma unroll
    for (int mf = 0; mf < 2; ++mf)
#pragma unroll
      for (int nf = 0; nf < 2; ++nf)
        acc[mf][nf] = __builtin_amdgcn_mfma_f32_16x16x32_f16(af[mf], bf[nf], acc[mf][nf], 0, 0, 0);
  }
  int r4 = lane >> 4;
#pragma unroll
  for (int nf = 0; nf < 2; ++nf) {
    int f = f0 + nf * 16 + lr;
    float bias = (f < 256) ? a1b[f] : a2b[f - 256];
#pragma unroll
    for (int mf = 0; mf < 2; ++mf) {
#pragma unroll
      for (int r = 0; r < 4; ++r) {
        int b = b0 + mf * 16 + r4 * 4 + r;
        float v = acc[mf][nf][r] + bias;
        ssq[b * 384 + f] = (_Float16)(v * v);
        if (f < 256) {
          int flat = (((b >> 4) * 8 + (f >> 5)) * 64 + ((f >> 3) & 3) * 16 + (b & 15)) * 8 + (f & 7);
          s1p[flat] = (_Float16)v;
        } else {
          s2h[b * 128 + (f - 256)] = (_Float16)v;
        }
      }
    }
  }
}

// ---------------- K_dmd: demod MFMA GEMM M=2048 N=192 K block-sparse -----
// grid (3, 32), block 256, tile 64x64
__global__ __launch_bounds__(256) void k_dmd(const _Float16* __restrict__ ssq,
    const _Float16* __restrict__ W2Th, float* __restrict__ d1,
    float* __restrict__ d2) {
  int t = threadIdx.x, lane = t & 63, w = t >> 6;
  int wr = w >> 1, wc = w & 1;
  int b0 = blockIdx.y * 64 + wr * 32;
  int o0 = blockIdx.x * 64 + wc * 32;
  int kbeg = (blockIdx.x == 2) ? 8 : 0;
  int kend = (blockIdx.x == 2) ? 12 : 8;
  f32x4 acc[2][2] = {};
  int lr = lane & 15, lk = (lane >> 4) * 8;
  for (int kg = kbeg; kg < kend; ++kg) {
    f16x8 af[2], bf[2];
#pragma unroll
    for (int mf = 0; mf < 2; ++mf)
      af[mf] = *(const f16x8*)(ssq + (b0 + mf * 16 + lr) * 384 + kg * 32 + lk);
#pragma unroll
    for (int nf = 0; nf < 2; ++nf)
      bf[nf] = *(const f16x8*)(W2Th + (o0 + nf * 16 + lr) * 384 + kg * 32 + lk);
#pragma unroll
    for (int mf = 0; mf < 2; ++mf)
#pragma unroll
      for (int nf = 0; nf < 2; ++nf)
        acc[mf][nf] = __builtin_amdgcn_mfma_f32_16x16x32_f16(af[mf], bf[nf], acc[mf][nf], 0, 0, 0);
  }
  int r4 = lane >> 4;
#pragma unroll
  for (int mf = 0; mf < 2; ++mf) {
#pragma unroll
    for (int r = 0; r < 4; ++r) {
      int b = b0 + mf * 16 + r4 * 4 + r;
#pragma unroll
      for (int nf = 0; nf < 2; ++nf) {
        int o = o0 + nf * 16 + lr;
        float v = rsqrtf(acc[mf][nf][r] + 1e-8f);
        if (o < 128) d1[b * 128 + o] = v;
        else         d2[b * 64 + (o - 128)] = v;
      }
    }
  }
}

// ---------------- K_l1: MFMA GEMM  M=2048(b) N=8192(p*128+o) K=256 -------
// epilogue writes PRE-MODULATED x1t = lrelu(y)*s2
__global__ __launch_bounds__(256) void k_l1(const _Float16* __restrict__ s1p,
    const _Float16* __restrict__ Ghp, const float* __restrict__ d1,
    const float* __restrict__ c1b, const _Float16* __restrict__ s2h,
    __half* __restrict__ x1t) {
  int t = threadIdx.x, lane = t & 63, w = t >> 6;
  int wr = w >> 1, wc = w & 1;
  int bq0 = blockIdx.y * 8 + wr * 4;
  int nq0 = blockIdx.x * 8 + wc * 4;
  f32x4 acc[4][4] = {};
#pragma unroll
  for (int kg = 0; kg < 8; ++kg) {
    f16x8 af[4], bf[4];
#pragma unroll
    for (int mf = 0; mf < 4; ++mf)
      af[mf] = *(const f16x8*)(s1p + (((bq0 + mf) * 8 + kg) * 64 + lane) * 8);
#pragma unroll
    for (int nf = 0; nf < 4; ++nf)
      bf[nf] = *(const f16x8*)(Ghp + (((nq0 + nf) * 8 + kg) * 64 + lane) * 8);
#pragma unroll
    for (int mf = 0; mf < 4; ++mf)
#pragma unroll
      for (int nf = 0; nf < 4; ++nf)
        acc[mf][nf] = __builtin_amdgcn_mfma_f32_16x16x32_f16(af[mf], bf[nf], acc[mf][nf], 0, 0, 0);
  }
  int nc = lane & 15, r4 = lane >> 4;
#pragma unroll
  for (int mf = 0; mf < 4; ++mf) {
#pragma unroll
    for (int r = 0; r < 4; ++r) {
      int b = (bq0 + mf) * 16 + r4 * 4 + r;
#pragma unroll
      for (int nf = 0; nf < 4; ++nf) {
        int n = (nq0 + nf) * 16 + nc;
        int o = n & 127, p = n >> 7;
        float v = acc[mf][nf][r] * d1[b * 128 + o] + c1b[o];
        v = (v >= 0.f) ? v : 0.2f * v;
        v *= (float)s2h[b * 128 + o];
        x1t[(b * 64 + p) * 128 + o] = (__half)v;
      }
    }
  }
}

// ---------------- K_l2: row-split upsample+conv (MFMA), 4 blocks/CU ------
// grid (2048 batch, 2 half), block 256 (4 waves, 2 rows/wave).
// LDS: xq dbuf 2 x [10 rows x 18][4 gran] = 22.5 KB + x1l 5 coarse rows = 10 KB.
// Quarter q (32 ch): 3 dx-groups x {4-row window, 3 dy x 8 MFMA}; builds of
// quarter q+1 spread across dx-groups; af ring 1-ahead (global w2p).
__global__ __launch_bounds__(256, 4) void k_l2(const __half* __restrict__ x1t,
    const float* __restrict__ d2g, const _Float16* __restrict__ w2p,
    const float* __restrict__ c2b, float* __restrict__ out) {
  int b = blockIdx.x, h = blockIdx.y, t = threadIdx.x;
  int lane = t & 63, w = t >> 6;
  __shared__ unsigned short xq[2][5760];   // [buf][90 pairs x 64]
  __shared__ unsigned short x1l[40 * 128]; // 5 coarse rows x 8 px, swizzled
  const __half* xb = x1t + b * 8192;
  const int cr0 = h ? 3 : 0;               // first coarse row staged
  const int padlr = h ? 9 : 0;             // local pad (zero) row

  // stage 5 coarse rows -> x1l (coalesced, swizzled granules)
  for (int idx = t; idx < 640; idx += 256) {
    int cp = idx >> 4, gc = idx & 15;
    f16x8 v = *(const f16x8*)(xb + (cr0 * 8 + cp) * 128 + gc * 8);
    int gs = (gc & 8) | ((gc ^ cp) & 7);
    *(f16x8*)&x1l[cp * 128 + gs * 8] = v;
  }
  // zero fill both buffers: pad row (18 px) + cols 0/17 rows 0..9 (20 px)
  {
    f16x8 z = {};
    for (int idx = t; idx < 304; idx += 256) {
      int pg = idx >> 3, gsel = idx & 7;
      int buf = gsel >> 2, i = gsel & 3;
      int pix;
      if (pg < 18) pix = padlr * 18 + pg;
      else { int j = pg - 18; pix = (j >> 1) * 18 + (j & 1) * 17; }
      *(f16x8*)&xq[buf][xq_off(pix, i)] = z;
    }
  }
  // af ring init: u=0 -> tap0 q0 (dx-major order: tap = dy*3+dx)
  f16x8 afb[2][4];
#pragma unroll
  for (int mf = 0; mf < 4; ++mf)
    afb[0][mf] = *(const f16x8*)(w2p + ((0 * 4 + mf) * 64 + lane) * 8);

  // build one granule: idx in [0,576): i = idx/144, p = idx-144i = (rowr,c)
  auto build_one = [&](int qn, int idx) {
    int i = idx / 144, p = idx - i * 144;
    int rowr = p >> 4, c = p & 15;
    int gfr = h ? 7 + rowr : rowr;          // global fine row 0..15
    int y0, y1, x0, x1i; float wy0, wy1, wx0, wx1;
    up_wi(gfr, 8, y0, y1, wy0, wy1);
    up_wi(c, 8, x0, x1i, wx0, wx1);
    int c00 = (y0 - cr0) * 8 + x0, c01 = (y0 - cr0) * 8 + x1i;
    int c10 = (y1 - cr0) * 8 + x0, c11 = (y1 - cr0) * 8 + x1i;
    int gc = qn * 4 + i;
    f16x8 va = *(const f16x8*)&x1l[c00 * 128 + ((gc & 8) | ((gc ^ c00) & 7)) * 8];
    f16x8 vb = *(const f16x8*)&x1l[c01 * 128 + ((gc & 8) | ((gc ^ c01) & 7)) * 8];
    f16x8 vc = *(const f16x8*)&x1l[c10 * 128 + ((gc & 8) | ((gc ^ c10) & 7)) * 8];
    f16x8 vd = *(const f16x8*)&x1l[c11 * 128 + ((gc & 8) | ((gc ^ c11) & 7)) * 8];
    f16x8 v = va * (_Float16)(wy0 * wx0);
    v += vb * (_Float16)(wy0 * wx1);
    v += vc * (_Float16)(wy1 * wx0);
    v += vd * (_Float16)(wy1 * wx1);
    int lr = rowr + (h ? 0 : 1);
    *(f16x8*)&xq[qn & 1][xq_off(lr * 18 + c + 1, i)] = v;
  };

  __syncthreads();            // x1l staged, borders zeroed
  for (int idx = t; idx < 576; idx += 256) build_one(0, idx);
  __syncthreads();            // xq[0] quarter-0 ready

  f32x4 acc[4][2] = {};
  f16x8 rw[4];
  int ig = lane >> 4, colb = lane & 15;

#pragma unroll
  for (int q = 0; q < 4; ++q) {
#pragma unroll
    for (int dx = 0; dx < 3; ++dx) {
      // 4-row window for this dx (rows w*2 .. w*2+3)
#pragma unroll
      for (int j = 0; j < 4; ++j) {
        int pix = (w * 2 + j) * 18 + colb + dx;
        rw[j] = *(const f16x8*)&xq[q & 1][xq_off(pix, ig)];
      }
      if (q < 3 && t < 192) build_one(q + 1, dx * 192 + t);
#pragma unroll
      for (int dy = 0; dy < 3; ++dy) {
        const int u = q * 9 + dx * 3 + dy;
        if (u + 1 < 36) {       // af prefetch 1 ahead (dx-major order)
          const int un = u + 1;
          const int qn = un / 9, rn = un - qn * 9;
          const int dxn = rn / 3, dyn = rn - dxn * 3;
          const int tapn = dyn * 3 + dxn;
#pragma unroll
          for (int mf = 0; mf < 4; ++mf)
            afb[un & 1][mf] = *(const f16x8*)(w2p + (((tapn * 4 + qn) * 4 + mf) * 64 + lane) * 8);
        }
        __builtin_amdgcn_s_setprio(1);
#pragma unroll
        for (int mf = 0; mf < 4; ++mf)
#pragma unroll
          for (int nf = 0; nf < 2; ++nf)
            acc[mf][nf] = __builtin_amdgcn_mfma_f32_16x16x32_f16(afb[u & 1][mf], rw[nf + dy], acc[mf][nf], 0, 0, 0);
        __builtin_amdgcn_s_setprio(0);
      }
    }
    if (q < 3) __syncthreads();   // builds visible; reads of xq[q&1] done
  }
  // epilogue: demod + bias + lrelu, f32 out (rows h*8 + w*2 + nf)
  int px = lane & 15, r4 = lane >> 4;
#pragma unroll
  for (int mf = 0; mf < 4; ++mf) {
#pragma unroll
    for (int r = 0; r < 4; ++r) {
      int o = mf * 16 + r4 * 4 + r;
      float dm = d2g[b * 64 + o], bias = c2b[o];
#pragma unroll
      for (int nf = 0; nf < 2; ++nf) {
        int gr = h * 8 + w * 2 + nf;
        float v = acc[mf][nf][r] * dm + bias;
        v = (v >= 0.f) ? v : 0.2f * v;
        out[(b * 64 + o) * 256 + gr * 16 + px] = v;
      }
    }
  }
}

extern "C" void kernel_launch(void* const* d_in, const int* in_sizes, int n_in,
                              void* d_out, int out_size, void* d_ws, size_t ws_size,
                              hipStream_t stream) {
  const float* w    = (const float*)d_in[0];
  const float* ic   = (const float*)d_in[1];
  const float* w0c  = (const float*)d_in[2];
  const float* b0   = (const float*)d_in[3];
  const float* a1w  = (const float*)d_in[4];
  const float* a1b  = (const float*)d_in[5];
  const float* w1c  = (const float*)d_in[6];
  const float* c1b  = (const float*)d_in[7];
  const float* a2w  = (const float*)d_in[8];
  const float* a2b  = (const float*)d_in[9];
  const float* w2c  = (const float*)d_in[10];
  const float* c2b  = (const float*)d_in[11];
  float* out = (float*)d_out;
  char* ws = (char*)d_ws;

  float*    x0u  = (float*)(ws + WS_X0U);
  _Float16* Ghp  = (_Float16*)(ws + WS_GHP);
  _Float16* w2p  = (_Float16*)(ws + WS_W2P);
  _Float16* wh   = (_Float16*)(ws + WS_WH);
  _Float16* afTh = (_Float16*)(ws + WS_AFTH);
  _Float16* W2Th = (_Float16*)(ws + WS_W2TH);
  _Float16* s1p  = (_Float16*)(ws + WS_S1P);
  _Float16* s2h  = (_Float16*)(ws + WS_S2H);
  _Float16* ssq  = (_Float16*)(ws + WS_SSQ);
  float*    d1   = (float*)(ws + WS_D1);
  float*    d2   = (float*)(ws + WS_D2);
  __half*   x1t  = (__half*)(ws + WS_X1T);

  k_init <<<256, 256, 0, stream>>>(ic, w0c, b0, x0u);
  dim3 gp(128, 4);
  k_prep <<<gp, 256, 0, stream>>>(w1c, x0u, Ghp);
  k_misc <<<5440, 256, 0, stream>>>(w1c, w2c, a1w, a2w, w, w2p, wh, afTh, W2Th);
  dim3 gs(6, 32);
  k_sty  <<<gs, 256, 0, stream>>>(wh, afTh, a1b, a2b, s1p, s2h, ssq);
  dim3 gd(3, 32);
  k_dmd  <<<gd, 256, 0, stream>>>(ssq, W2Th, d1, d2);
  dim3 g1(64, 16);
  k_l1   <<<g1, 256, 0, stream>>>(s1p, Ghp, d1, c1b, s2h, x1t);
  dim3 gl2(2048, 2);
  k_l2   <<<gl2, 256, 0, stream>>>(x1t, d2, w2p, c2b, out);
}

// Round 12
// 139.482 us; speedup vs baseline: 1.2795x; 1.2795x over previous
//
#include <hip/hip_runtime.h>
#include <hip/hip_fp16.h>

typedef _Float16 f16x8 __attribute__((ext_vector_type(8)));
typedef float f32x4 __attribute__((ext_vector_type(4)));

// ---------------- workspace layout (bytes) ----------------
#define WS_X0U   0            // 256*64*4   = 65536      x0u f32 [c][64]
#define WS_GHP   65536        // 8192*256*2 = 4194304    Ghp f16 frag-packed [n][c]
#define WS_W2P   4259840      // 73728*2    = 147456     w2 f16 frag-packed
#define WS_WH    4407296      // 2048*512*2 = 2097152    w f16 [b][k]
#define WS_AFTH  6504448      // 384*512*2  = 393216     affine wt f16 [f][k]
#define WS_W2TH  6897664      // 192*384*2  = 147456     sum_k W^2 f16 [o][k]
#define WS_S1P   7045120      // 2048*256*2 = 1048576    style1 f16 frag-packed
#define WS_S2H   8093696      // 2048*128*2 = 524288     style2 f16 [b][c]
#define WS_SSQ   8617984      // 2048*384*2 = 1572864    style^2 f16 [b][f]
#define WS_D1    10190848     // 2048*128*4 = 1048576    demod1
#define WS_D2    11239424     // 2048*64*4  = 524288     demod2
#define WS_X1T   11763712     // 2048*64*128*2 = 33554432  x1t f16 [b][p][o] PRE-MODULATED
// end 45318144

// bilinear x2, half-pixel centers
__device__ __forceinline__ void up_wi(int j, int S, int& i0, int& i1,
                                      float& w0, float& w1) {
  int m = j >> 1;
  if (j & 1) { i0 = m; i1 = (m + 1 < S) ? m + 1 : S - 1; w0 = 0.75f; w1 = 0.25f; }
  else       { i0 = (m - 1 >= 0) ? m - 1 : 0; i1 = m;     w0 = 0.25f; w1 = 0.75f; }
}

// xq LDS addressing: pixel-pair layout, 8 slots/pair, XOR swizzle.
// units: ushorts. pair = 64 ushorts (8 slots x 8), slot = ((pix&1)*4+i)^((pix>>1)&7)
__device__ __forceinline__ int xq_off(int pix, int i) {
  return (pix >> 1) * 64 + (((((pix & 1) << 2) + i) ^ ((pix >> 1) & 7)) << 3);
}

// ---------------- K0: init conv + lrelu + upsample 4->8 ----------------
// grid 256 (o), block 256. Flat j=(c,tap) sweep: 18 coalesced w0c loads/thread,
// all 16 pixels accumulated in registers; 2-stage LDS reduce.
__global__ __launch_bounds__(256) void k_init(const float* __restrict__ ic,
    const float* __restrict__ w0c, const float* __restrict__ b0,
    float* __restrict__ x0u) {
  int o = blockIdx.x, t = threadIdx.x;
  __shared__ float xl[512 * 16];      // 32 KB staged ic
  __shared__ float part[16 * 257];    // padded stride: conflict-free reduce
  __shared__ float part2[16 * 17];
  __shared__ float x4[16];
  for (int i = t; i < 512 * 16; i += 256) xl[i] = ic[i];
  __syncthreads();
  float acc[16];
#pragma unroll
  for (int p = 0; p < 16; ++p) acc[p] = 0.f;
#pragma unroll
  for (int it = 0; it < 18; ++it) {
    int j = it * 256 + t;             // j in [0, 4608)
    float wv = w0c[o * 4608 + j];     // coalesced
    int c = j / 9, k = j - c * 9;
    int dy = k / 3, dx = k - dy * 3;
    const float* xc = &xl[c * 16];
#pragma unroll
    for (int p = 0; p < 16; ++p) {
      int py = p >> 2, px = p & 3;
      int iy = py + dy - 1, ix = px + dx - 1;
      bool ok = ((unsigned)iy < 4u) && ((unsigned)ix < 4u);
      float xv = ok ? xc[iy * 4 + ix] : 0.f;
      acc[p] += wv * xv;
    }
  }
#pragma unroll
  for (int p = 0; p < 16; ++p) part[p * 257 + t] = acc[p];
  __syncthreads();
  {                                    // stage 1: 256 thr, 16 adds each
    int p = t & 15, ch = t >> 4;
    float s = 0.f;
#pragma unroll
    for (int g = 0; g < 16; ++g) s += part[p * 257 + ch * 16 + g];
    part2[p * 17 + ch] = s;
  }
  __syncthreads();
  if (t < 16) {
    float v = b0[o];
#pragma unroll
    for (int g = 0; g < 16; ++g) v += part2[t * 17 + g];
    x4[t] = (v >= 0.f) ? v : 0.2f * v;
  }
  __syncthreads();
  if (t < 64) {
    int oy = t >> 3, ox = t & 7;
    int y0, y1, xx0, xx1; float wy0, wy1, wx0, wx1;
    up_wi(oy, 4, y0, y1, wy0, wy1);
    up_wi(ox, 4, xx0, xx1, wx0, wx1);
    float v = wy0 * (wx0 * x4[y0 * 4 + xx0] + wx1 * x4[y0 * 4 + xx1])
            + wy1 * (wx0 * x4[y1 * 4 + xx0] + wx1 * x4[y1 * 4 + xx1]);
    x0u[o * 64 + t] = v;
  }
}

// ---------------- K_prep: Ghp[n=p*128+o][c] frag-packed f16 --------------
// grid (128 o, 4 pgroup), block 256 (c)
__global__ __launch_bounds__(256) void k_prep(const float* __restrict__ w1c,
    const float* __restrict__ x0u, _Float16* __restrict__ Ghp) {
  int o = blockIdx.x, pg = blockIdx.y, t = threadIdx.x;
  __shared__ _Float16 x0l[256][66];
  for (int i = t; i < 256 * 64; i += 256) {
    int c = i >> 6, p = i & 63;
    x0l[c][p] = (_Float16)x0u[i];
  }
  __syncthreads();
  int c = t;
  float wr9[9];
#pragma unroll
  for (int k = 0; k < 9; ++k) wr9[k] = w1c[(o * 256 + c) * 9 + k];
  int cpart = ((((c >> 3) & 3) * 16 + (o & 15)) * 8) + (c & 7);
  int cq = c >> 5, oq = o >> 4;
  for (int p = pg * 16; p < pg * 16 + 16; ++p) {
    int py = p >> 3, px = p & 7;
    float acc = 0.f;
#pragma unroll
    for (int dy = 0; dy < 3; ++dy) {
      int iy = py + dy - 1;
      if ((unsigned)iy >= 8u) continue;
#pragma unroll
      for (int dx = 0; dx < 3; ++dx) {
        int ix = px + dx - 1;
        if ((unsigned)ix >= 8u) continue;
        acc += wr9[dy * 3 + dx] * (float)x0l[c][iy * 8 + ix];
      }
    }
    Ghp[((p * 8 + oq) * 8 + cq) * 512 + cpart] = (_Float16)acc;
  }
}

// ---------------- K_misc: w2p, wh, afTh, W2Th ----------------------------
// grid 5440, block 256
__global__ __launch_bounds__(256) void k_misc(const float* __restrict__ w1c,
    const float* __restrict__ w2c, const float* __restrict__ a1w,
    const float* __restrict__ a2w, const float* __restrict__ wsrc,
    _Float16* __restrict__ w2p, _Float16* __restrict__ wh,
    _Float16* __restrict__ afTh, _Float16* __restrict__ W2Th) {
  int idx = blockIdx.x * 256 + threadIdx.x;
  if (idx < 73728) {
    int tap = idx / 8192, r = idx & 8191;
    int kg = r >> 11, mf = (r >> 9) & 3, l = (r >> 3) & 63, j = r & 7;
    int o = mf * 16 + (l & 15);
    int c = kg * 32 + (l >> 4) * 8 + j;
    w2p[idx] = (_Float16)w2c[(o * 128 + c) * 9 + tap];
  } else if (idx < 73728 + 1048576) {
    int i = idx - 73728;
    wh[i] = (_Float16)wsrc[i];
  } else if (idx < 73728 + 1048576 + 196608) {
    int i = idx - 73728 - 1048576;         // i = f*512 + k
    afTh[i] = (_Float16)((i < 131072) ? a1w[i] : a2w[i - 131072]);
  } else if (idx < 73728 + 1048576 + 196608 + 73728) {
    int i = idx - 73728 - 1048576 - 196608;  // i = o*384 + k
    int o = i / 384, k = i - o * 384;
    float v = 0.f;
    const float* wp = nullptr;
    if (o < 128 && k < 256)        wp = w1c + (o * 256 + k) * 9;
    else if (o >= 128 && k >= 256) wp = w2c + ((o - 128) * 128 + (k - 256)) * 9;
    if (wp) {
#pragma unroll
      for (int q = 0; q < 9; ++q) v += wp[q] * wp[q];
    }
    W2Th[i] = (_Float16)v;
  }
}

// ---------------- K_sty: styles MFMA GEMM M=2048 N=384 K=512 -------------
// grid (6, 32), block 256 (4 waves 2x2), tile 64x64
__global__ __launch_bounds__(256) void k_sty(const _Float16* __restrict__ wh,
    const _Float16* __restrict__ afTh, const float* __restrict__ a1b,
    const float* __restrict__ a2b, _Float16* __restrict__ s1p,
    _Float16* __restrict__ s2h, _Float16* __restrict__ ssq) {
  int t = threadIdx.x, lane = t & 63, w = t >> 6;
  int wr = w >> 1, wc = w & 1;
  int b0 = blockIdx.y * 64 + wr * 32;
  int f0 = blockIdx.x * 64 + wc * 32;
  f32x4 acc[2][2] = {};
  int lr = lane & 15, lk = (lane >> 4) * 8;
#pragma unroll
  for (int kg = 0; kg < 16; ++kg) {
    f16x8 af[2], bf[2];
#pragma unroll
    for (int mf = 0; mf < 2; ++mf)
      af[mf] = *(const f16x8*)(wh + (b0 + mf * 16 + lr) * 512 + kg * 32 + lk);
#pragma unroll
    for (int nf = 0; nf < 2; ++nf)
      bf[nf] = *(const f16x8*)(afTh + (f0 + nf * 16 + lr) * 512 + kg * 32 + lk);
#pragma unroll
    for (int mf = 0; mf < 2; ++mf)
#pragma unroll
      for (int nf = 0; nf < 2; ++nf)
        acc[mf][nf] = __builtin_amdgcn_mfma_f32_16x16x32_f16(af[mf], bf[nf], acc[mf][nf], 0, 0, 0);
  }
  int r4 = lane >> 4;
#pragma unroll
  for (int nf = 0; nf < 2; ++nf) {
    int f = f0 + nf * 16 + lr;
    float bias = (f < 256) ? a1b[f] : a2b[f - 256];
#pragma unroll
    for (int mf = 0; mf < 2; ++mf) {
#pragma unroll
      for (int r = 0; r < 4; ++r) {
        int b = b0 + mf * 16 + r4 * 4 + r;
        float v = acc[mf][nf][r] + bias;
        ssq[b * 384 + f] = (_Float16)(v * v);
        if (f < 256) {
          int flat = (((b >> 4) * 8 + (f >> 5)) * 64 + ((f >> 3) & 3) * 16 + (b & 15)) * 8 + (f & 7);
          s1p[flat] = (_Float16)v;
        } else {
          s2h[b * 128 + (f - 256)] = (_Float16)v;
        }
      }
    }
  }
}

// ---------------- K_dmd: demod MFMA GEMM M=2048 N=192 K block-sparse -----
// grid (3, 32), block 256, tile 64x64
__global__ __launch_bounds__(256) void k_dmd(const _Float16* __restrict__ ssq,
    const _Float16* __restrict__ W2Th, float* __restrict__ d1,
    float* __restrict__ d2) {
  int t = threadIdx.x, lane = t & 63, w = t >> 6;
  int wr = w >> 1, wc = w & 1;
  int b0 = blockIdx.y * 64 + wr * 32;
  int o0 = blockIdx.x * 64 + wc * 32;
  int kbeg = (blockIdx.x == 2) ? 8 : 0;
  int kend = (blockIdx.x == 2) ? 12 : 8;
  f32x4 acc[2][2] = {};
  int lr = lane & 15, lk = (lane >> 4) * 8;
  for (int kg = kbeg; kg < kend; ++kg) {
    f16x8 af[2], bf[2];
#pragma unroll
    for (int mf = 0; mf < 2; ++mf)
      af[mf] = *(const f16x8*)(ssq + (b0 + mf * 16 + lr) * 384 + kg * 32 + lk);
#pragma unroll
    for (int nf = 0; nf < 2; ++nf)
      bf[nf] = *(const f16x8*)(W2Th + (o0 + nf * 16 + lr) * 384 + kg * 32 + lk);
#pragma unroll
    for (int mf = 0; mf < 2; ++mf)
#pragma unroll
      for (int nf = 0; nf < 2; ++nf)
        acc[mf][nf] = __builtin_amdgcn_mfma_f32_16x16x32_f16(af[mf], bf[nf], acc[mf][nf], 0, 0, 0);
  }
  int r4 = lane >> 4;
#pragma unroll
  for (int mf = 0; mf < 2; ++mf) {
#pragma unroll
    for (int r = 0; r < 4; ++r) {
      int b = b0 + mf * 16 + r4 * 4 + r;
#pragma unroll
      for (int nf = 0; nf < 2; ++nf) {
        int o = o0 + nf * 16 + lr;
        float v = rsqrtf(acc[mf][nf][r] + 1e-8f);
        if (o < 128) d1[b * 128 + o] = v;
        else         d2[b * 64 + (o - 128)] = v;
      }
    }
  }
}

// ---------------- K_l1: MFMA GEMM  M=2048(b) N=8192(p*128+o) K=256 -------
// epilogue writes PRE-MODULATED x1t = lrelu(y)*s2
__global__ __launch_bounds__(256) void k_l1(const _Float16* __restrict__ s1p,
    const _Float16* __restrict__ Ghp, const float* __restrict__ d1,
    const float* __restrict__ c1b, const _Float16* __restrict__ s2h,
    __half* __restrict__ x1t) {
  int t = threadIdx.x, lane = t & 63, w = t >> 6;
  int wr = w >> 1, wc = w & 1;
  int bq0 = blockIdx.y * 8 + wr * 4;
  int nq0 = blockIdx.x * 8 + wc * 4;
  f32x4 acc[4][4] = {};
#pragma unroll
  for (int kg = 0; kg < 8; ++kg) {
    f16x8 af[4], bf[4];
#pragma unroll
    for (int mf = 0; mf < 4; ++mf)
      af[mf] = *(const f16x8*)(s1p + (((bq0 + mf) * 8 + kg) * 64 + lane) * 8);
#pragma unroll
    for (int nf = 0; nf < 4; ++nf)
      bf[nf] = *(const f16x8*)(Ghp + (((nq0 + nf) * 8 + kg) * 64 + lane) * 8);
#pragma unroll
    for (int mf = 0; mf < 4; ++mf)
#pragma unroll
      for (int nf = 0; nf < 4; ++nf)
        acc[mf][nf] = __builtin_amdgcn_mfma_f32_16x16x32_f16(af[mf], bf[nf], acc[mf][nf], 0, 0, 0);
  }
  int nc = lane & 15, r4 = lane >> 4;
#pragma unroll
  for (int mf = 0; mf < 4; ++mf) {
#pragma unroll
    for (int r = 0; r < 4; ++r) {
      int b = (bq0 + mf) * 16 + r4 * 4 + r;
#pragma unroll
      for (int nf = 0; nf < 4; ++nf) {
        int n = (nq0 + nf) * 16 + nc;
        int o = n & 127, p = n >> 7;
        float v = acc[mf][nf][r] * d1[b * 128 + o] + c1b[o];
        v = (v >= 0.f) ? v : 0.2f * v;
        v *= (float)s2h[b * 128 + o];
        x1t[(b * 64 + p) * 128 + o] = (__half)v;
      }
    }
  }
}

// ---------------- K_l2: quarter-pipelined upsample+conv, dx-major --------
// grid 2048 (batch), block 256 (4 waves), 2 blocks/CU.  (R10 structure)
__global__ __launch_bounds__(256, 2) void k_l2(const __half* __restrict__ x1t,
    const float* __restrict__ d2g, const _Float16* __restrict__ w2p,
    const float* __restrict__ c2b, float* __restrict__ out) {
  int b = blockIdx.x, t = threadIdx.x;
  int lane = t & 63, w = t >> 6;
  __shared__ unsigned short xq[2][9792];     // [buf][pair-swizzled granules]
  __shared__ unsigned short x1l[64 * 128];   // both channel halves, swizzled
  const __half* xb = x1t + b * 8192;

  for (int idx = t; idx < 1024; idx += 256) {
    int q = idx >> 4, gc = idx & 15;
    f16x8 v = *(const f16x8*)(xb + q * 128 + gc * 8);
    int gs = (gc & 8) | ((gc ^ q) & 7);
    *(f16x8*)&x1l[q * 128 + gs * 8] = v;
  }
  {
    f16x8 z = {};
    for (int idx = t; idx < 400; idx += 256) {
      int pg = idx >> 3, g = idx & 7;
      int buf = g >> 2, i = g & 3;
      int pix;
      if (pg < 18) pix = 288 + pg;                                 // row 16
      else { int j = pg - 18; pix = (j >> 1) * 18 + (j & 1) * 17; } // cols 0/17
      *(f16x8*)&xq[buf][xq_off(pix, i)] = z;
    }
  }
  f16x8 afb[3][4];
#pragma unroll
  for (int mf = 0; mf < 4; ++mf) {
    afb[0][mf] = *(const f16x8*)(w2p + (((0 * 4 + 0) * 4 + mf) * 64 + lane) * 8);
    afb[1][mf] = *(const f16x8*)(w2p + (((3 * 4 + 0) * 4 + mf) * 64 + lane) * 8);
  }
  int fy = t >> 4, fx = t & 15;
  int y0, y1, x0, x1i; float wy0, wy1, wx0, wx1;
  up_wi(fy, 8, y0, y1, wy0, wy1);
  up_wi(fx, 8, x0, x1i, wx0, wx1);
  _Float16 wA = (_Float16)(wy0 * wx0), wB = (_Float16)(wy0 * wx1);
  _Float16 wC = (_Float16)(wy1 * wx0), wD = (_Float16)(wy1 * wx1);
  int pixb = fy * 18 + fx + 1;
  int q00 = y0 * 8 + x0, q01 = y0 * 8 + x1i, q10 = y1 * 8 + x0, q11 = y1 * 8 + x1i;

  auto build_granule = [&](int qn, int i) {
    int gc = qn * 4 + i;
    f16x8 va = *(const f16x8*)&x1l[q00 * 128 + ((gc & 8) | ((gc ^ q00) & 7)) * 8];
    f16x8 vb = *(const f16x8*)&x1l[q01 * 128 + ((gc & 8) | ((gc ^ q01) & 7)) * 8];
    f16x8 vc = *(const f16x8*)&x1l[q10 * 128 + ((gc & 8) | ((gc ^ q10) & 7)) * 8];
    f16x8 vd = *(const f16x8*)&x1l[q11 * 128 + ((gc & 8) | ((gc ^ q11) & 7)) * 8];
    f16x8 v = va * wA;
    v += vb * wB;
    v += vc * wC;
    v += vd * wD;
    *(f16x8*)&xq[qn & 1][xq_off(pixb, i)] = v;
  };

  __syncthreads();
#pragma unroll
  for (int i = 0; i < 4; ++i) build_granule(0, i);
  __syncthreads();

  f32x4 acc[4][4] = {};
  f16x8 rw[2][6];
  int ig = lane >> 4;
  int colb = lane & 15;

  auto read_win = [&](int qb, int buf, int dx) {
#pragma unroll
    for (int j = 0; j < 6; ++j) {
      int fr = w * 4 + j - 1;
      int srow = ((unsigned)fr < 16u) ? fr : 16;
      int pix = srow * 18 + colb + dx;
      rw[buf][j] = *(const f16x8*)&xq[qb][xq_off(pix, ig)];
    }
  };

#pragma unroll
  for (int q = 0; q < 4; ++q) {
    read_win(q & 1, 0, 0);
#pragma unroll
    for (int dx = 0; dx < 3; ++dx) {
      if (dx < 2) read_win(q & 1, (dx + 1) & 1, dx + 1);
      if (q < 3) {
        if (dx == 0) { build_granule(q + 1, 0); build_granule(q + 1, 1); }
        else if (dx == 1) build_granule(q + 1, 2);
        else              build_granule(q + 1, 3);
      }
#pragma unroll
      for (int dy = 0; dy < 3; ++dy) {
        const int u = q * 9 + dx * 3 + dy;
        if (u + 2 < 36) {
          const int un = u + 2;
          const int qn = un / 9, rn = un - qn * 9;
          const int dxn = rn / 3, dyn = rn - dxn * 3;
          const int tapn = dyn * 3 + dxn;
#pragma unroll
          for (int mf = 0; mf < 4; ++mf)
            afb[un % 3][mf] = *(const f16x8*)(w2p + (((tapn * 4 + qn) * 4 + mf) * 64 + lane) * 8);
        }
        __builtin_amdgcn_s_setprio(1);
#pragma unroll
        for (int mf = 0; mf < 4; ++mf)
#pragma unroll
          for (int nf = 0; nf < 4; ++nf)
            acc[mf][nf] = __builtin_amdgcn_mfma_f32_16x16x32_f16(afb[u % 3][mf], rw[dx & 1][nf + dy], acc[mf][nf], 0, 0, 0);
        __builtin_amdgcn_s_setprio(0);
      }
    }
    if (q < 3) __syncthreads();
  }
  int px = lane & 15, r4 = lane >> 4;
#pragma unroll
  for (int mf = 0; mf < 4; ++mf) {
#pragma unroll
    for (int r = 0; r < 4; ++r) {
      int o = mf * 16 + r4 * 4 + r;
      float dm = d2g[b * 64 + o], bias = c2b[o];
#pragma unroll
      for (int nf = 0; nf < 4; ++nf) {
        int py = w * 4 + nf;
        float v = acc[mf][nf][r] * dm + bias;
        v = (v >= 0.f) ? v : 0.2f * v;
        out[(b * 64 + o) * 256 + py * 16 + px] = v;
      }
    }
  }
}

extern "C" void kernel_launch(void* const* d_in, const int* in_sizes, int n_in,
                              void* d_out, int out_size, void* d_ws, size_t ws_size,
                              hipStream_t stream) {
  const float* w    = (const float*)d_in[0];
  const float* ic   = (const float*)d_in[1];
  const float* w0c  = (const float*)d_in[2];
  const float* b0   = (const float*)d_in[3];
  const float* a1w  = (const float*)d_in[4];
  const float* a1b  = (const float*)d_in[5];
  const float* w1c  = (const float*)d_in[6];
  const float* c1b  = (const float*)d_in[7];
  const float* a2w  = (const float*)d_in[8];
  const float* a2b  = (const float*)d_in[9];
  const float* w2c  = (const float*)d_in[10];
  const float* c2b  = (const float*)d_in[11];
  float* out = (float*)d_out;
  char* ws = (char*)d_ws;

  float*    x0u  = (float*)(ws + WS_X0U);
  _Float16* Ghp  = (_Float16*)(ws + WS_GHP);
  _Float16* w2p  = (_Float16*)(ws + WS_W2P);
  _Float16* wh   = (_Float16*)(ws + WS_WH);
  _Float16* afTh = (_Float16*)(ws + WS_AFTH);
  _Float16* W2Th = (_Float16*)(ws + WS_W2TH);
  _Float16* s1p  = (_Float16*)(ws + WS_S1P);
  _Float16* s2h  = (_Float16*)(ws + WS_S2H);
  _Float16* ssq  = (_Float16*)(ws + WS_SSQ);
  float*    d1   = (float*)(ws + WS_D1);
  float*    d2   = (float*)(ws + WS_D2);
  __half*   x1t  = (__half*)(ws + WS_X1T);

  k_init <<<256, 256, 0, stream>>>(ic, w0c, b0, x0u);
  dim3 gp(128, 4);
  k_prep <<<gp, 256, 0, stream>>>(w1c, x0u, Ghp);
  k_misc <<<5440, 256, 0, stream>>>(w1c, w2c, a1w, a2w, w, w2p, wh, afTh, W2Th);
  dim3 gs(6, 32);
  k_sty  <<<gs, 256, 0, stream>>>(wh, afTh, a1b, a2b, s1p, s2h, ssq);
  dim3 gd(3, 32);
  k_dmd  <<<gd, 256, 0, stream>>>(ssq, W2Th, d1, d2);
  dim3 g1(64, 16);
  k_l1   <<<g1, 256, 0, stream>>>(s1p, Ghp, d1, c1b, s2h, x1t);
  k_l2   <<<2048, 256, 0, stream>>>(x1t, d2, w2p, c2b, out);
}